// Round 2
// baseline (878.683 us; speedup 1.0000x reference)
//
#include <hip/hip_runtime.h>

typedef unsigned short u16;
typedef unsigned int   u32;
typedef __attribute__((ext_vector_type(4))) float floatx4;
typedef __attribute__((ext_vector_type(8))) short shortx8;

#define BB 8192
#define SS 18
#define DD 512

// ---------- helpers ----------
__device__ __forceinline__ u16 f2bf(float f){            // RNE f32->bf16
  u32 u = __float_as_uint(f);
  return (u16)((u + 0x7FFFu + ((u >> 16) & 1u)) >> 16);
}

__device__ __forceinline__ shortx8 pack8(const float* p){
  floatx4 a = *(const floatx4*)p;
  floatx4 b = *(const floatx4*)(p + 4);
  shortx8 t;
  t[0]=(short)f2bf(a[0]); t[1]=(short)f2bf(a[1]); t[2]=(short)f2bf(a[2]); t[3]=(short)f2bf(a[3]);
  t[4]=(short)f2bf(b[0]); t[5]=(short)f2bf(b[1]); t[6]=(short)f2bf(b[2]); t[7]=(short)f2bf(b[3]);
  return t;
}

// write 4x16B to LDS row-major [row][64k] tile with XOR swizzle
__device__ __forceinline__ void lds_store4(u16* buf, int row, int rowBytes, int khByte,
                                           int swzMask, const shortx8* v){
#pragma unroll
  for (int q=0;q<4;++q){
    int off = row*rowBytes + khByte + q*16;
    off ^= (row & swzMask) << 4;
    *(shortx8*)((char*)buf + off) = v[q];
  }
}

// stage one 64-k chunk (rows = tid>>1, k-half = tid&1) from a bf16 source
__device__ __forceinline__ void stage_bf16(u16* buf, const u16* gsrc, size_t srcRowBytes, int tid){
  int row = tid >> 1, kh = tid & 1;
  const char* p = (const char*)gsrc + (size_t)row*srcRowBytes + kh*64;
  shortx8 v[4];
#pragma unroll
  for (int q=0;q<4;++q) v[q] = *(const shortx8*)(p + q*16);
  lds_store4(buf, row, 128, kh*64, 7, v);
}

// same but from fp32 source with convert
__device__ __forceinline__ void stage_f32(u16* buf, const float* gsrc, size_t srcRowFloats, int tid){
  int row = tid >> 1, kh = tid & 1;
  const float* p = gsrc + (size_t)row*srcRowFloats + kh*32;
  shortx8 v[4];
#pragma unroll
  for (int q=0;q<4;++q) v[q] = pack8(p + q*8);
  lds_store4(buf, row, 128, kh*64, 7, v);
}

// fragment read: 8 contiguous bf16 at (row, k = kByte/2 + (lane>>4)*8)
__device__ __forceinline__ shortx8 lds_frag(const u16* buf, int row, int rowBytes, int kByte,
                                            int swzMask, int lane){
  int off = row*rowBytes + kByte + ((lane>>4)<<4);
  off ^= (row & swzMask) << 4;
  return *(const shortx8*)((const char*)buf + off);
}

// one BK=64 chunk of MFMAs; As:[128][64] bf16 swizzled, Bs:[Nrows][64]
template<int MF, int NF>
__device__ __forceinline__ void mma64(const u16* As, const u16* Bs, int wm, int wn, int lane,
                                      floatx4 acc[MF][NF]){
#pragma unroll
  for (int kk=0; kk<2; ++kk){
    shortx8 a[MF], b[NF];
#pragma unroll
    for (int i=0;i<MF;++i) a[i] = lds_frag(As, wm + i*16 + (lane&15), 128, kk*64, 7, lane);
#pragma unroll
    for (int j=0;j<NF;++j) b[j] = lds_frag(Bs, wn + j*16 + (lane&15), 128, kk*64, 7, lane);
#pragma unroll
    for (int i=0;i<MF;++i)
#pragma unroll
      for (int j=0;j<NF;++j)
        acc[i][j] = __builtin_amdgcn_mfma_f32_16x16x32_bf16(a[i], b[j], acc[i][j], 0, 0, 0);
  }
}

// ---------- prep: fp32 (S,K,N) -> bf16 (S,N,Kpad), pad zeroed ----------
__global__ __launch_bounds__(256) void transpose_w(const float* __restrict__ src,
                                                   u16* __restrict__ dst,
                                                   int K, int N, int Kpad){
  __shared__ float tile[32][33];
  int s = blockIdx.z;
  int k0 = blockIdx.x*32, n0 = blockIdx.y*32;
  int tx = threadIdx.x & 31, ty = threadIdx.x >> 5;
#pragma unroll
  for (int r=0;r<4;++r){
    int k = k0 + ty*4 + r;
    float v = (k < K) ? src[((size_t)s*K + k)*N + n0 + tx] : 0.f;
    tile[ty*4+r][tx] = v;
  }
  __syncthreads();
#pragma unroll
  for (int r=0;r<4;++r){
    int n = n0 + ty*4 + r;
    dst[((size_t)s*N + n)*Kpad + k0 + tx] = f2bf(tile[tx][ty*4+r]);
  }
}

// ---------- bn: h2 = (relu(gs @ w1 + b1)) @ w2 + b2  -> h2b (B,S,32) bf16 ----------
__global__ __launch_bounds__(256) void k_bn(const float* __restrict__ gs,
     const u16* __restrict__ w1t, const u16* __restrict__ w2t,
     const float* __restrict__ b1, const float* __restrict__ b2,
     u16* __restrict__ h2b){
  __shared__ __align__(16) u16 As[128*64];   // 16KB
  __shared__ __align__(16) u16 Bs[32*64];    // 4KB
  __shared__ __align__(16) u16 G1[128*32];   // 8KB (h1 bf16, rowBytes 64, swz 3)
  __shared__ __align__(16) u16 W2s[32*32];   // 2KB
  int tid = threadIdx.x, lane = tid & 63, w = tid >> 6;
  int s = blockIdx.y, m0 = blockIdx.x * 128;
  floatx4 acc[2][2] = {};
  const float* Ab = gs + ((size_t)m0*SS + s)*DD;
  const u16*   Bb = w1t + (size_t)s*32*512;
  for (int c=0;c<8;++c){
    __syncthreads();
    stage_f32(As, Ab + c*64, (size_t)SS*DD, tid);
    if (tid < 64) stage_bf16(Bs, Bb + c*64, 1024, tid);
    __syncthreads();
    mma64<2,2>(As, Bs, w*32, 0, lane, acc);
  }
  // epilogue1: relu(acc+b1) -> G1
#pragma unroll
  for (int i=0;i<2;++i)
#pragma unroll
   for (int j=0;j<2;++j){
    int col = j*16 + (lane&15);
    float bias = b1[s*32 + col];
#pragma unroll
    for (int r=0;r<4;++r){
      int row = w*32 + i*16 + ((lane>>4)<<2) + r;
      float v = fmaxf(acc[i][j][r] + bias, 0.f);
      int off = (row*64 + col*2) ^ ((row&3)<<4);
      *(u16*)((char*)G1 + off) = f2bf(v);
    }
  }
  if (tid < 32){
    const u16* p = w2t + (size_t)s*32*32 + tid*32;
#pragma unroll
    for (int q=0;q<4;++q){
      int off = (tid*64 + q*16) ^ ((tid&3)<<4);
      *(shortx8*)((char*)W2s + off) = *(const shortx8*)(p + q*8);
    }
  }
  __syncthreads();
  floatx4 acc2[2][2] = {};
  {
    shortx8 a[2], b[2];
#pragma unroll
    for (int i=0;i<2;++i) a[i] = lds_frag(G1,  w*32 + i*16 + (lane&15), 64, 0, 3, lane);
#pragma unroll
    for (int j=0;j<2;++j) b[j] = lds_frag(W2s, j*16 + (lane&15),       64, 0, 3, lane);
#pragma unroll
    for (int i=0;i<2;++i)
#pragma unroll
      for (int j=0;j<2;++j)
        acc2[i][j] = __builtin_amdgcn_mfma_f32_16x16x32_bf16(a[i], b[j], acc2[i][j], 0,0,0);
  }
#pragma unroll
  for (int i=0;i<2;++i)
#pragma unroll
   for (int j=0;j<2;++j){
    int col = j*16 + (lane&15);
    float bias = b2[s*32 + col];
#pragma unroll
    for (int r=0;r<4;++r){
      int row = w*32 + i*16 + ((lane>>4)<<2) + r;
      h2b[((size_t)(m0+row)*SS + s)*32 + col] = f2bf(acc2[i][j][r] + bias);
    }
  }
}

// ---------- gm + age: gfa (B,144) bf16 ----------
__global__ __launch_bounds__(256) void k_gm(const u16* __restrict__ h2b,
     const u16* __restrict__ w1t, const u16* __restrict__ w2t,
     const float* __restrict__ b1, const float* __restrict__ b2,
     const float* __restrict__ ta, const float* __restrict__ aw1, const float* __restrict__ ab1,
     const float* __restrict__ aw2, const float* __restrict__ ab2,
     u16* __restrict__ gfab){
  __shared__ __align__(16) u16 As[128*64];
  __shared__ __align__(16) u16 Bs[128*64];
  __shared__ __align__(16) u16 G1[128*128];  // 32KB, rowBytes 256, swz 7
  int tid=threadIdx.x, lane=tid&63, w=tid>>6;
  int m0 = blockIdx.x*128;
  floatx4 acc[2][8] = {};
  for (int c=0;c<9;++c){
    __syncthreads();
    stage_bf16(As, h2b + (size_t)m0*576 + c*64, 1152, tid);
    stage_bf16(Bs, w1t + c*64,                 1152, tid);
    __syncthreads();
    mma64<2,8>(As, Bs, w*32, 0, lane, acc);
  }
#pragma unroll
  for (int i=0;i<2;++i)
#pragma unroll
   for (int j=0;j<8;++j){
    int col = j*16 + (lane&15);
    float bias = b1[col];
#pragma unroll
    for (int r=0;r<4;++r){
      int row = w*32 + i*16 + ((lane>>4)<<2) + r;
      float v = fmaxf(acc[i][j][r] + bias, 0.f);
      int off = (row*256 + col*2) ^ ((row&7)<<4);
      *(u16*)((char*)G1 + off) = f2bf(v);
    }
  }
  floatx4 acc2[2][8] = {};
  for (int c2=0;c2<2;++c2){
    __syncthreads();
    stage_bf16(Bs, w2t + c2*64, 256, tid);
    __syncthreads();
#pragma unroll
    for (int kk=0;kk<2;++kk){
      shortx8 a[2], b[8];
#pragma unroll
      for (int i=0;i<2;++i){
        int row = w*32 + i*16 + (lane&15);
        int off = (row*256 + c2*128 + kk*64 + ((lane>>4)<<4)) ^ ((row&7)<<4);
        a[i] = *(const shortx8*)((const char*)G1 + off);
      }
#pragma unroll
      for (int j=0;j<8;++j) b[j] = lds_frag(Bs, j*16 + (lane&15), 128, kk*64, 7, lane);
#pragma unroll
      for (int i=0;i<2;++i)
#pragma unroll
        for (int j=0;j<8;++j)
          acc2[i][j] = __builtin_amdgcn_mfma_f32_16x16x32_bf16(a[i], b[j], acc2[i][j], 0,0,0);
    }
  }
#pragma unroll
  for (int i=0;i<2;++i)
#pragma unroll
   for (int j=0;j<8;++j){
    int col = j*16 + (lane&15);
    float bias = b2[col];
#pragma unroll
    for (int r=0;r<4;++r){
      int row = w*32 + i*16 + ((lane>>4)<<2) + r;
      gfab[(size_t)(m0+row)*144 + col] = f2bf(acc2[i][j][r] + bias);
    }
  }
  if (tid < 128){
    int bidx = m0 + tid;
    float t = ta[bidx];
    float a1[16];
#pragma unroll
    for (int j2=0;j2<16;++j2){ float v = t*aw1[j2] + ab1[j2]; a1[j2] = fmaxf(v, 0.f); }
#pragma unroll
    for (int m=0;m<16;++m){
      float v = ab2[m];
#pragma unroll
      for (int j2=0;j2<16;++j2) v += a1[j2]*aw2[j2*16+m];
      gfab[(size_t)bidx*144 + 128 + m] = f2bf(v);
    }
  }
}

// ---------- fc1: y1 = relu([gfa|gs] @ w1 + b1) -> y1b (B,S,512) bf16 ----------
__global__ __launch_bounds__(256) void k_fc1(const u16* __restrict__ gfab,
     const float* __restrict__ gs, const u16* __restrict__ w1t,
     const float* __restrict__ b1, u16* __restrict__ y1b){
  __shared__ __align__(16) u16 SM[128*64*2];   // As | Bs, reused as 128x128 bf16 outbuf
  u16* As = SM; u16* Bs = SM + 128*64;
  int tid=threadIdx.x, lane=tid&63, w=tid>>6;
  int m0 = blockIdx.x*128, n0 = blockIdx.y*128, s = blockIdx.z;
  int wm = (w>>1)*64, wn = (w&1)*64;
  floatx4 acc[4][4] = {};
  const u16* Bb = w1t + ((size_t)s*512 + n0)*704;
  for (int c=0;c<11;++c){                       // K = 704 (656 padded)
    __syncthreads();
    {
      int row = tid>>1, kh = tid&1, bidx = m0+row;
      shortx8 v[4];
      if (c < 2){                               // pure gfa (bf16)
        const u16* p = gfab + (size_t)bidx*144 + c*64 + kh*32;
#pragma unroll
        for (int q=0;q<4;++q) v[q] = *(const shortx8*)(p + q*8);
      } else if (c >= 3 && c <= 9){             // pure gs (fp32 -> bf16)
        const float* p = gs + ((size_t)bidx*SS + s)*DD + (c*64 - 144) + kh*32;
#pragma unroll
        for (int q=0;q<4;++q) v[q] = pack8(p + q*8);
      } else {                                  // straddle chunks c==2, c==10
#pragma unroll
        for (int q=0;q<4;++q){
          shortx8 t;
#pragma unroll
          for (int e=0;e<8;++e){
            int k = c*64 + kh*32 + q*8 + e;
            u16 val;
            if (k < 144)      val = gfab[(size_t)bidx*144 + k];
            else if (k < 656) val = f2bf(gs[((size_t)bidx*SS + s)*DD + (k-144)]);
            else              val = 0;
            t[e] = (short)val;
          }
          v[q] = t;
        }
      }
      lds_store4(As, row, 128, kh*64, 7, v);
    }
    stage_bf16(Bs, Bb + c*64, 1408, tid);
    __syncthreads();
    mma64<4,4>(As, Bs, wm, wn, lane, acc);
  }
  __syncthreads();
  // relu(acc+b1) -> SM [128][128] bf16 (swizzled), then coalesced 16B stores
#pragma unroll
  for (int i=0;i<4;++i)
#pragma unroll
   for (int j=0;j<4;++j){
    int col = wn + j*16 + (lane&15);
    float bias = b1[(size_t)s*512 + n0 + col];
#pragma unroll
    for (int r=0;r<4;++r){
      int row = wm + i*16 + ((lane>>4)<<2) + r;
      float v = fmaxf(acc[i][j][r] + bias, 0.f);
      int off = (row*256 + col*2) ^ ((row&7)<<4);
      *(u16*)((char*)SM + off) = f2bf(v);
    }
  }
  __syncthreads();
  {
    int row = tid>>1, half = tid&1;
    u16* gp = y1b + ((size_t)(m0+row)*SS + s)*DD + n0 + half*64;
#pragma unroll
    for (int q=0;q<8;++q){                      // FIX: q<8 (was q<4) — full 64-col half-row
      int off = (row*256 + half*128 + q*16) ^ ((row&7)<<4);
      *(shortx8*)(gp + q*8) = *(const shortx8*)((const char*)SM + off);
    }
  }
}

// ---------- fc2: out = y1 @ w2 + b2 + gs  (fp32 out) ----------
__global__ __launch_bounds__(256) void k_fc2(const u16* __restrict__ y1b,
     const float* __restrict__ gs, const u16* __restrict__ w2t,
     const float* __restrict__ b2, float* __restrict__ out){
  __shared__ __align__(16) float SMF[128*128]; // 64KB; front 32KB doubles as As|Bs
  u16* As = (u16*)SMF; u16* Bs = As + 128*64;
  int tid=threadIdx.x, lane=tid&63, w=tid>>6;
  int m0 = blockIdx.x*128, n0 = blockIdx.y*128, s = blockIdx.z;
  int wm = (w>>1)*64, wn = (w&1)*64;
  floatx4 acc[4][4] = {};
  const u16* Abase = y1b + ((size_t)m0*SS + s)*DD;
  const u16* Bb    = w2t + ((size_t)s*512 + n0)*512;
  for (int c=0;c<8;++c){
    __syncthreads();
    stage_bf16(As, Abase + c*64, (size_t)SS*DD*2, tid);
    stage_bf16(Bs, Bb + c*64, 1024, tid);
    __syncthreads();
    mma64<4,4>(As, Bs, wm, wn, lane, acc);
  }
  __syncthreads();
#pragma unroll
  for (int i=0;i<4;++i)
#pragma unroll
   for (int j=0;j<4;++j){
    int col = wn + j*16 + (lane&15);
#pragma unroll
    for (int r=0;r<4;++r){
      int row = wm + i*16 + ((lane>>4)<<2) + r;
      int off = (row*512 + col*4) ^ ((row&7)<<4);
      *(float*)((char*)SMF + off) = acc[i][j][r];
    }
  }
  __syncthreads();
  {
    int row = tid>>1, half = tid&1;
    size_t gidx = ((size_t)(m0+row)*SS + s)*DD + n0 + half*64;
    const float* bp = b2 + (size_t)s*512 + n0 + half*64;
#pragma unroll
    for (int q=0;q<16;++q){
      int off = (row*512 + half*256 + q*16) ^ ((row&7)<<4);
      floatx4 v = *(const floatx4*)((const char*)SMF + off);
      floatx4 g = *(const floatx4*)(gs + gidx + q*4);
      floatx4 bb = *(const floatx4*)(bp + q*4);
      *(floatx4*)(out + gidx + q*4) = v + g + bb;
    }
  }
}

// ---------- launch ----------
extern "C" void kernel_launch(void* const* d_in, const int* in_sizes, int n_in,
                              void* d_out, int out_size, void* d_ws, size_t ws_size,
                              hipStream_t stream){
  (void)in_sizes; (void)n_in; (void)out_size; (void)ws_size;
  const float* gs   = (const float*)d_in[1];   // local_styles (d_in[0]) is unused by the reference
  const float* ta   = (const float*)d_in[2];
  const float* bnw1 = (const float*)d_in[3];
  const float* bnb1 = (const float*)d_in[4];
  const float* bnw2 = (const float*)d_in[5];
  const float* bnb2 = (const float*)d_in[6];
  const float* gmw1 = (const float*)d_in[7];
  const float* gmb1 = (const float*)d_in[8];
  const float* gmw2 = (const float*)d_in[9];
  const float* gmb2 = (const float*)d_in[10];
  const float* aw1  = (const float*)d_in[11];
  const float* ab1  = (const float*)d_in[12];
  const float* aw2  = (const float*)d_in[13];
  const float* ab2  = (const float*)d_in[14];
  const float* fcw1 = (const float*)d_in[15];
  const float* fcb1 = (const float*)d_in[16];
  const float* fcw2 = (const float*)d_in[17];
  const float* fcb2 = (const float*)d_in[18];

  char* ws = (char*)d_ws;                       // ~178 MB total
  u16* fcW1t = (u16*)(ws + 0);                  // 18*512*704*2 = 12,976,128
  u16* fcW2t = (u16*)(ws + 12976128);           //  9,437,184
  u16* bnW1t = (u16*)(ws + 22413312);           //    589,824
  u16* bnW2t = (u16*)(ws + 23003136);           //     36,864
  u16* gmW1t = (u16*)(ws + 23040000);           //    147,456
  u16* gmW2t = (u16*)(ws + 23187456);           //     32,768
  u16* h2b   = (u16*)(ws + 23220224);           //  9,437,184
  u16* gfab  = (u16*)(ws + 32657408);           //  2,359,296
  u16* y1b   = (u16*)(ws + 35016704);           // 150,994,944  (end 186,011,648)
  float* out = (float*)d_out;

  dim3 blk(256);
  transpose_w<<<dim3(16,1,18),  blk, 0, stream>>>(bnw1, bnW1t, 512, 32, 512);
  transpose_w<<<dim3(1,1,18),   blk, 0, stream>>>(bnw2, bnW2t, 32, 32, 32);
  transpose_w<<<dim3(18,4,1),   blk, 0, stream>>>(gmw1, gmW1t, 576, 128, 576);
  transpose_w<<<dim3(4,4,1),    blk, 0, stream>>>(gmw2, gmW2t, 128, 128, 128);
  transpose_w<<<dim3(22,16,18), blk, 0, stream>>>(fcw1, fcW1t, 656, 512, 704);
  transpose_w<<<dim3(16,16,18), blk, 0, stream>>>(fcw2, fcW2t, 512, 512, 512);

  k_bn <<<dim3(64,18),   blk, 0, stream>>>(gs, bnW1t, bnW2t, bnb1, bnb2, h2b);
  k_gm <<<dim3(64),      blk, 0, stream>>>(h2b, gmW1t, gmW2t, gmb1, gmb2, ta, aw1, ab1, aw2, ab2, gfab);
  k_fc1<<<dim3(64,4,18), blk, 0, stream>>>(gfab, gs, fcW1t, fcb1, y1b);
  k_fc2<<<dim3(64,4,18), blk, 0, stream>>>(y1b, gs, fcW2t, fcb2, out);
}

// Round 4
// 687.054 us; speedup vs baseline: 1.2789x; 1.2789x over previous
//
#include <hip/hip_runtime.h>

typedef unsigned short u16;
typedef unsigned int   u32;
typedef __attribute__((ext_vector_type(4))) float floatx4;
typedef __attribute__((ext_vector_type(8))) short shortx8;

#define BB 8192
#define SS 18
#define DD 512

// ---------- helpers ----------
__device__ __forceinline__ u16 f2bf(float f){            // RNE f32->bf16
  u32 u = __float_as_uint(f);
  return (u16)((u + 0x7FFFu + ((u >> 16) & 1u)) >> 16);
}

__device__ __forceinline__ shortx8 pack8v(floatx4 a, floatx4 b){
  shortx8 t;
  t[0]=(short)f2bf(a[0]); t[1]=(short)f2bf(a[1]); t[2]=(short)f2bf(a[2]); t[3]=(short)f2bf(a[3]);
  t[4]=(short)f2bf(b[0]); t[5]=(short)f2bf(b[1]); t[6]=(short)f2bf(b[2]); t[7]=(short)f2bf(b[3]);
  return t;
}

// async global->LDS, 16B per lane, linear LDS dest (wave-uniform base + lane*16)
__device__ __forceinline__ void gload16(const void* g, void* l){
  __builtin_amdgcn_global_load_lds((const __attribute__((address_space(1))) void*)g,
                                   (__attribute__((address_space(3))) void*)l, 16, 0, 0);
}

// stage a [ROWS][64] bf16 chunk as the XOR-swizzled image via global_load_lds.
// LDS slot (row, blk16) holds global 16B block (blk16 ^ (row&7)) of that row.
template<int CALLS>
__device__ __forceinline__ void gstage(const char* src, size_t rowStrideB, int chunkByteOff,
                                       char* lds, int wid, int lane){
#pragma unroll
  for (int i=0;i<CALLS;++i){
    int base = (wid*CALLS + i)*1024;
    int off  = base + lane*16;
    int row  = off >> 7;
    int blk  = ((off >> 4) & 7) ^ (row & 7);
    gload16(src + (size_t)row*rowStrideB + chunkByteOff + blk*16, lds + base);
  }
}

// reg-staged LDS write of 4x16B for one row-half, same swizzled image
__device__ __forceinline__ void lds_store4(char* buf, int row, int rowBytes, int khByte,
                                           int swzMask, const shortx8* v){
#pragma unroll
  for (int q=0;q<4;++q){
    int off = row*rowBytes + khByte + q*16;
    off ^= (row & swzMask) << 4;
    *(shortx8*)(buf + off) = v[q];
  }
}

__device__ __forceinline__ void stage_bf16(char* buf, const u16* gsrc, size_t srcRowBytes, int tid){
  int row = tid >> 1, kh = tid & 1;
  const char* p = (const char*)gsrc + (size_t)row*srcRowBytes + kh*64;
  shortx8 v[4];
#pragma unroll
  for (int q=0;q<4;++q) v[q] = *(const shortx8*)(p + q*16);
  lds_store4(buf, row, 128, kh*64, 7, v);
}

__device__ __forceinline__ shortx8 lds_frag(const char* buf, int row, int rowBytes, int kByte,
                                            int swzMask, int lane){
  int off = row*rowBytes + kByte + ((lane>>4)<<4);
  off ^= (row & swzMask) << 4;
  return *(const shortx8*)(buf + off);
}

template<int MF, int NF>
__device__ __forceinline__ void mma64(const char* As, const char* Bs, int wm, int wn, int lane,
                                      floatx4 acc[MF][NF]){
#pragma unroll
  for (int kk=0; kk<2; ++kk){
    shortx8 a[MF], b[NF];
#pragma unroll
    for (int i=0;i<MF;++i) a[i] = lds_frag(As, wm + i*16 + (lane&15), 128, kk*64, 7, lane);
#pragma unroll
    for (int j=0;j<NF;++j) b[j] = lds_frag(Bs, wn + j*16 + (lane&15), 128, kk*64, 7, lane);
#pragma unroll
    for (int i=0;i<MF;++i)
#pragma unroll
      for (int j=0;j<NF;++j)
        acc[i][j] = __builtin_amdgcn_mfma_f32_16x16x32_bf16(a[i], b[j], acc[i][j], 0, 0, 0);
  }
}

// bijective XCD chunking (nwg % 8 == 0)
__device__ __forceinline__ int xcd_swz(int bid, int nwg){
  int q = nwg >> 3;
  return (bid & 7)*q + (bid >> 3);
}

// ---------- prep: fp32 (S,Ksrc,N) slice [kSrcOff, kSrcOff+Kuse) -> bf16 (S,N,Kpad) at kDstOff ----------
__global__ __launch_bounds__(256) void transpose_w2(const float* __restrict__ src,
                                                    u16* __restrict__ dst,
                                                    int sKstride, int kSrcOff, int Kuse,
                                                    int N, int Kpad, int kDstOff){
  __shared__ float tile[32][33];
  int s = blockIdx.z;
  int k0 = blockIdx.x*32, n0 = blockIdx.y*32;
  int tx = threadIdx.x & 31, ty = threadIdx.x >> 5;
#pragma unroll
  for (int r=0;r<4;++r){
    int k = k0 + ty*4 + r;
    float v = (k < Kuse) ? src[((size_t)s*sKstride + kSrcOff + k)*N + n0 + tx] : 0.f;
    tile[ty*4+r][tx] = v;
  }
  __syncthreads();
#pragma unroll
  for (int r=0;r<4;++r){
    int n = n0 + ty*4 + r;
    dst[((size_t)s*N + n)*Kpad + kDstOff + k0 + tx] = f2bf(tile[tx][ty*4+r]);
  }
}

// ---------- bn: h2 = (relu(gs @ w1 + b1)) @ w2 + b2 -> h2b (B,S,32) bf16 ----------
__global__ __launch_bounds__(256) void k_bn(const float* __restrict__ gs,
     const u16* __restrict__ w1t, const u16* __restrict__ w2t,
     const float* __restrict__ b1, const float* __restrict__ b2,
     u16* __restrict__ h2b){
  __shared__ __align__(16) char SMB[40960];
  int tid = threadIdx.x, lane = tid & 63, wid = tid >> 6;
  int nb = xcd_swz(blockIdx.x, 1152);
  int m0 = (nb & 63)*128, s = nb >> 6;
  floatx4 acc[2][2] = {};
  const char*  Bsrc = (const char*)w1t + (size_t)s*32*1024;
  const float* Ags  = gs + ((size_t)(m0 + (tid>>1))*SS + s)*DD + (tid&1)*32;
  floatx4 fr[8];
  // prologue: chunk 0
  gstage<1>((const char*)Bsrc, 1024, 0, SMB+32768, wid, lane);
#pragma unroll
  for (int q=0;q<8;++q) fr[q] = *(const floatx4*)(Ags + q*4);
  for (int c=0;c<8;++c){
    char* Asc = SMB + (c&1)*16384;
    char* Bsc = SMB + 32768 + (c&1)*4096;
    { shortx8 v[4];
#pragma unroll
      for (int q=0;q<4;++q) v[q] = pack8v(fr[2*q], fr[2*q+1]);
      lds_store4(Asc, tid>>1, 128, (tid&1)*64, 7, v); }
    __syncthreads();
    int cn = c+1;
    if (cn < 8){
      gstage<1>(Bsrc, 1024, cn*128, SMB + 32768 + (cn&1)*4096, wid, lane);
      const float* p = Ags + cn*64;
#pragma unroll
      for (int q=0;q<8;++q) fr[q] = *(const floatx4*)(p + q*4);
    }
    mma64<2,2>(Asc, Bsc, wid*32, 0, lane, acc);
  }
  __syncthreads();
  // epilogue1: relu(acc+b1) -> G1 (SMB) [128][32] bf16 (rowBytes 64, swz 3)
  char* G1  = SMB;
  char* W2s = SMB + 8192;
#pragma unroll
  for (int i=0;i<2;++i)
#pragma unroll
   for (int j=0;j<2;++j){
    int col = j*16 + (lane&15);
    float bias = b1[s*32 + col];
#pragma unroll
    for (int r=0;r<4;++r){
      int row = wid*32 + i*16 + ((lane>>4)<<2) + r;
      float v = fmaxf(acc[i][j][r] + bias, 0.f);
      int off = (row*64 + col*2) ^ ((row&3)<<4);
      *(u16*)(G1 + off) = f2bf(v);
    }
  }
  if (tid < 32){
    const u16* p = w2t + (size_t)s*32*32 + tid*32;
#pragma unroll
    for (int q=0;q<4;++q){
      int off = (tid*64 + q*16) ^ ((tid&3)<<4);
      *(shortx8*)(W2s + off) = *(const shortx8*)(p + q*8);
    }
  }
  __syncthreads();
  floatx4 acc2[2][2] = {};
  {
    shortx8 a[2], b[2];
#pragma unroll
    for (int i=0;i<2;++i) a[i] = lds_frag(G1,  wid*32 + i*16 + (lane&15), 64, 0, 3, lane);
#pragma unroll
    for (int j=0;j<2;++j) b[j] = lds_frag(W2s, j*16 + (lane&15),          64, 0, 3, lane);
#pragma unroll
    for (int i=0;i<2;++i)
#pragma unroll
      for (int j=0;j<2;++j)
        acc2[i][j] = __builtin_amdgcn_mfma_f32_16x16x32_bf16(a[i], b[j], acc2[i][j], 0,0,0);
  }
#pragma unroll
  for (int i=0;i<2;++i)
#pragma unroll
   for (int j=0;j<2;++j){
    int col = j*16 + (lane&15);
    float bias = b2[s*32 + col];
#pragma unroll
    for (int r=0;r<4;++r){
      int row = wid*32 + i*16 + ((lane>>4)<<2) + r;
      h2b[((size_t)(m0+row)*SS + s)*32 + col] = f2bf(acc2[i][j][r] + bias);
    }
  }
}

// ---------- gm + age: gfa (B,192) bf16 (cols 144..191 zero) ----------
__global__ __launch_bounds__(256) void k_gm(const u16* __restrict__ h2b,
     const u16* __restrict__ w1t, const u16* __restrict__ w2t,
     const float* __restrict__ b1, const float* __restrict__ b2,
     const float* __restrict__ ta, const float* __restrict__ aw1, const float* __restrict__ ab1,
     const float* __restrict__ aw2, const float* __restrict__ ab2,
     u16* __restrict__ gfab){
  __shared__ __align__(16) char As[128*128];
  __shared__ __align__(16) char Bs[128*128];
  __shared__ __align__(16) char G1[128*256];
  int tid=threadIdx.x, lane=tid&63, w=tid>>6;
  int m0 = blockIdx.x*128;
  floatx4 acc[2][8] = {};
  for (int c=0;c<9;++c){
    __syncthreads();
    stage_bf16(As, h2b + (size_t)m0*576 + c*64, 1152, tid);
    stage_bf16(Bs, w1t + c*64,                 1152, tid);
    __syncthreads();
    mma64<2,8>(As, Bs, w*32, 0, lane, acc);
  }
#pragma unroll
  for (int i=0;i<2;++i)
#pragma unroll
   for (int j=0;j<8;++j){
    int col = j*16 + (lane&15);
    float bias = b1[col];
#pragma unroll
    for (int r=0;r<4;++r){
      int row = w*32 + i*16 + ((lane>>4)<<2) + r;
      float v = fmaxf(acc[i][j][r] + bias, 0.f);
      int off = (row*256 + col*2) ^ ((row&7)<<4);
      *(u16*)(G1 + off) = f2bf(v);
    }
  }
  floatx4 acc2[2][8] = {};
  for (int c2=0;c2<2;++c2){
    __syncthreads();
    stage_bf16(Bs, w2t + c2*64, 256, tid);
    __syncthreads();
#pragma unroll
    for (int kk=0;kk<2;++kk){
      shortx8 a[2], b[8];
#pragma unroll
      for (int i=0;i<2;++i){
        int row = w*32 + i*16 + (lane&15);
        int off = (row*256 + c2*128 + kk*64 + ((lane>>4)<<4)) ^ ((row&7)<<4);
        a[i] = *(const shortx8*)(G1 + off);
      }
#pragma unroll
      for (int j=0;j<8;++j) b[j] = lds_frag(Bs, j*16 + (lane&15), 128, kk*64, 7, lane);
#pragma unroll
      for (int i=0;i<2;++i)
#pragma unroll
        for (int j=0;j<8;++j)
          acc2[i][j] = __builtin_amdgcn_mfma_f32_16x16x32_bf16(a[i], b[j], acc2[i][j], 0,0,0);
    }
  }
#pragma unroll
  for (int i=0;i<2;++i)
#pragma unroll
   for (int j=0;j<8;++j){
    int col = j*16 + (lane&15);
    float bias = b2[col];
#pragma unroll
    for (int r=0;r<4;++r){
      int row = w*32 + i*16 + ((lane>>4)<<2) + r;
      gfab[(size_t)(m0+row)*192 + col] = f2bf(acc2[i][j][r] + bias);
    }
  }
  if (tid < 128){
    int bidx = m0 + tid;
    float t = ta[bidx];
    float a1[16];
#pragma unroll
    for (int j2=0;j2<16;++j2){ float v = t*aw1[j2] + ab1[j2]; a1[j2] = fmaxf(v, 0.f); }
#pragma unroll
    for (int m=0;m<16;++m){
      float v = ab2[m];
#pragma unroll
      for (int j2=0;j2<16;++j2) v += a1[j2]*aw2[j2*16+m];
      gfab[(size_t)bidx*192 + 128 + m] = f2bf(v);
    }
    shortx8 zz = {};
#pragma unroll
    for (int z=0;z<6;++z) *(shortx8*)(gfab + (size_t)bidx*192 + 144 + z*8) = zz;
  }
}

// ---------- fc1: y1 = relu([gfa|pad|gs] @ w1 + b1) -> y1b (B,S,512) bf16 ----------
__global__ __launch_bounds__(256) void k_fc1(const u16* __restrict__ gfab,
     const float* __restrict__ gs, const u16* __restrict__ w1t,
     const float* __restrict__ b1, u16* __restrict__ y1b){
  __shared__ __align__(16) char SMB[65536];
  int tid=threadIdx.x, lane=tid&63, wid=tid>>6;
  int nb = xcd_swz(blockIdx.x, 4608);
  int n0 = (nb&3)*128, m0 = ((nb>>2)&63)*128, s = nb>>8;
  int wm=(wid>>1)*64, wn=(wid&1)*64;
  floatx4 acc[4][4] = {};
  const char*  Asrc0 = (const char*)gfab + (size_t)m0*384;
  const char*  Bsrc  = (const char*)w1t + ((size_t)s*512 + n0)*1408;
  const float* Ags   = gs + ((size_t)(m0 + (tid>>1))*SS + s)*DD + (tid&1)*32;
  floatx4 fr[8];
  // prologue: chunk 0 (bf16 from gfab)
  gstage<4>(Asrc0, 384, 0, SMB, wid, lane);
  gstage<4>(Bsrc, 1408, 0, SMB+32768, wid, lane);
  for (int c=0;c<11;++c){
    char* Asc = SMB + (c&1)*16384;
    char* Bsc = SMB + 32768 + (c&1)*16384;
    if (c >= 3){                       // fp32 chunk: ds_write prefetched regs
      shortx8 v[4];
#pragma unroll
      for (int q=0;q<4;++q) v[q] = pack8v(fr[2*q], fr[2*q+1]);
      lds_store4(Asc, tid>>1, 128, (tid&1)*64, 7, v);
    }
    __syncthreads();
    int cn = c+1;
    if (cn < 11){
      gstage<4>(Bsrc, 1408, cn*128, SMB + 32768 + (cn&1)*16384, wid, lane);
      if (cn < 3){
        gstage<4>(Asrc0, 384, cn*128, SMB + (cn&1)*16384, wid, lane);
      } else {
        const float* p = Ags + (cn*64 - 192);
#pragma unroll
        for (int q=0;q<8;++q) fr[q] = *(const floatx4*)(p + q*4);
      }
    }
    mma64<4,4>(Asc, Bsc, wm, wn, lane, acc);
  }
  __syncthreads();
  // epilogue: relu(acc+b1) -> SMB [128][128] bf16 swizzled, then 16B coalesced stores
  char* OT = SMB;
#pragma unroll
  for (int i=0;i<4;++i)
#pragma unroll
   for (int j=0;j<4;++j){
    int col = wn + j*16 + (lane&15);
    float bias = b1[(size_t)s*512 + n0 + col];
#pragma unroll
    for (int r=0;r<4;++r){
      int row = wm + i*16 + ((lane>>4)<<2) + r;
      float v = fmaxf(acc[i][j][r] + bias, 0.f);
      int off = (row*256 + col*2) ^ ((row&7)<<4);
      *(u16*)(OT + off) = f2bf(v);
    }
  }
  __syncthreads();
  {
    int row = tid>>1, half = tid&1;
    u16* gp = y1b + ((size_t)(m0+row)*SS + s)*DD + n0 + half*64;
#pragma unroll
    for (int q=0;q<8;++q){
      int off = (row*256 + half*128 + q*16) ^ ((row&7)<<4);
      *(shortx8*)(gp + q*8) = *(const shortx8*)(OT + off);
    }
  }
}

// ---------- fc2: out = y1 @ w2 + b2 + gs (fp32 out) ----------
__global__ __launch_bounds__(256) void k_fc2(const u16* __restrict__ y1b,
     const float* __restrict__ gs, const u16* __restrict__ w2t,
     const float* __restrict__ b2, float* __restrict__ out){
  __shared__ __align__(16) char SMB[65536];
  int tid=threadIdx.x, lane=tid&63, wid=tid>>6;
  int nb = xcd_swz(blockIdx.x, 4608);
  int n0 = (nb&3)*128, m0 = ((nb>>2)&63)*128, s = nb>>8;
  int wm=(wid>>1)*64, wn=(wid&1)*64;
  floatx4 acc[4][4] = {};
  const char* Asrc = (const char*)y1b + ((size_t)m0*SS + s)*1024;
  const char* Bsrc = (const char*)w2t + ((size_t)s*512 + n0)*1024;
  gstage<4>(Asrc, (size_t)SS*1024, 0, SMB, wid, lane);
  gstage<4>(Bsrc, 1024, 0, SMB+32768, wid, lane);
  for (int c=0;c<8;++c){
    char* Asc = SMB + (c&1)*16384;
    char* Bsc = SMB + 32768 + (c&1)*16384;
    __syncthreads();
    int cn = c+1;
    if (cn < 8){
      gstage<4>(Asrc, (size_t)SS*1024, cn*128, SMB + (cn&1)*16384, wid, lane);
      gstage<4>(Bsrc, 1024, cn*128, SMB + 32768 + (cn&1)*16384, wid, lane);
    }
    mma64<4,4>(Asc, Bsc, wm, wn, lane, acc);
  }
  __syncthreads();
  // epilogue: acc -> SMB as fp32 [128][128] swizzled, then 16B coalesced out-stores
  float* SMF = (float*)SMB;
#pragma unroll
  for (int i=0;i<4;++i)
#pragma unroll
   for (int j=0;j<4;++j){
    int col = wn + j*16 + (lane&15);
#pragma unroll
    for (int r=0;r<4;++r){
      int row = wm + i*16 + ((lane>>4)<<2) + r;
      int off = (row*512 + col*4) ^ ((row&7)<<4);
      *(float*)((char*)SMF + off) = acc[i][j][r];
    }
  }
  __syncthreads();
  {
    int row = tid>>1, half = tid&1;
    size_t gidx = ((size_t)(m0+row)*SS + s)*DD + n0 + half*64;
    const float* bp = b2 + (size_t)s*512 + n0 + half*64;
#pragma unroll
    for (int q=0;q<16;++q){
      int off = (row*512 + half*256 + q*16) ^ ((row&7)<<4);
      floatx4 v = *(const floatx4*)((const char*)SMF + off);
      floatx4 g = *(const floatx4*)(gs + gidx + q*4);
      floatx4 bb = *(const floatx4*)(bp + q*4);
      *(floatx4*)(out + gidx + q*4) = v + g + bb;
    }
  }
}

// ---------- launch ----------
extern "C" void kernel_launch(void* const* d_in, const int* in_sizes, int n_in,
                              void* d_out, int out_size, void* d_ws, size_t ws_size,
                              hipStream_t stream){
  (void)in_sizes; (void)n_in; (void)out_size; (void)ws_size;
  const float* gs   = (const float*)d_in[1];
  const float* ta   = (const float*)d_in[2];
  const float* bnw1 = (const float*)d_in[3];
  const float* bnb1 = (const float*)d_in[4];
  const float* bnw2 = (const float*)d_in[5];
  const float* bnb2 = (const float*)d_in[6];
  const float* gmw1 = (const float*)d_in[7];
  const float* gmb1 = (const float*)d_in[8];
  const float* gmw2 = (const float*)d_in[9];
  const float* gmb2 = (const float*)d_in[10];
  const float* aw1  = (const float*)d_in[11];
  const float* ab1  = (const float*)d_in[12];
  const float* aw2  = (const float*)d_in[13];
  const float* ab2  = (const float*)d_in[14];
  const float* fcw1 = (const float*)d_in[15];
  const float* fcb1 = (const float*)d_in[16];
  const float* fcw2 = (const float*)d_in[17];
  const float* fcb2 = (const float*)d_in[18];

  char* ws = (char*)d_ws;                       // ~187 MB total
  u16* fcW1t = (u16*)(ws + 0);                  // 18*512*704*2 = 12,976,128
  u16* fcW2t = (u16*)(ws + 12976128);           //  9,437,184
  u16* bnW1t = (u16*)(ws + 22413312);           //    589,824
  u16* bnW2t = (u16*)(ws + 23003136);           //     36,864
  u16* gmW1t = (u16*)(ws + 23040000);           //    147,456
  u16* gmW2t = (u16*)(ws + 23187456);           //     32,768
  u16* h2b   = (u16*)(ws + 23220224);           //  9,437,184
  u16* gfab  = (u16*)(ws + 32657408);           //  3,145,728 (B x 192)
  u16* y1b   = (u16*)(ws + 35803136);           // 150,994,944 (end 186,798,080)
  float* out = (float*)d_out;

  dim3 blk(256);
  // weights -> bf16, N-major, k-contiguous (padded where noted)
  transpose_w2<<<dim3(16,1,18),  blk, 0, stream>>>(bnw1, bnW1t, 512, 0, 512,  32, 512, 0);
  transpose_w2<<<dim3(1,1,18),   blk, 0, stream>>>(bnw2, bnW2t,  32, 0,  32,  32,  32, 0);
  transpose_w2<<<dim3(18,4,1),   blk, 0, stream>>>(gmw1, gmW1t, 576, 0, 576, 128, 576, 0);
  transpose_w2<<<dim3(4,4,1),    blk, 0, stream>>>(gmw2, gmW2t, 128, 0, 128, 128, 128, 0);
  transpose_w2<<<dim3(6,16,18),  blk, 0, stream>>>(fcw1, fcW1t, 656, 0,   144, 512, 704, 0);    // gfa part + zero pad to 192
  transpose_w2<<<dim3(16,16,18), blk, 0, stream>>>(fcw1, fcW1t, 656, 144, 512, 512, 704, 192);  // gs part at k=192
  transpose_w2<<<dim3(16,16,18), blk, 0, stream>>>(fcw2, fcW2t, 512, 0, 512, 512, 512, 0);

  k_bn <<<dim3(1152), blk, 0, stream>>>(gs, bnW1t, bnW2t, bnb1, bnb2, h2b);
  k_gm <<<dim3(64),   blk, 0, stream>>>(h2b, gmW1t, gmW2t, gmb1, gmb2, ta, aw1, ab1, aw2, ab2, gfab);
  k_fc1<<<dim3(4608), blk, 0, stream>>>(gfab, gs, fcW1t, fcb1, y1b);
  k_fc2<<<dim3(4608), blk, 0, stream>>>(y1b, gs, fcW2t, fcb2, out);
}

// Round 5
// 573.436 us; speedup vs baseline: 1.5323x; 1.1981x over previous
//
#include <hip/hip_runtime.h>

typedef unsigned short u16;
typedef unsigned int   u32;
typedef __attribute__((ext_vector_type(4))) float floatx4;
typedef __attribute__((ext_vector_type(8))) short shortx8;

#define BB 8192
#define SS 18
#define DD 512

// ---------- helpers ----------
__device__ __forceinline__ u16 f2bf(float f){            // RNE f32->bf16
  u32 u = __float_as_uint(f);
  return (u16)((u + 0x7FFFu + ((u >> 16) & 1u)) >> 16);
}
__device__ __forceinline__ float bf2f(u16 x){ return __uint_as_float(((u32)x)<<16); }

__device__ __forceinline__ shortx8 pack8v(floatx4 a, floatx4 b){
  shortx8 t;
  t[0]=(short)f2bf(a[0]); t[1]=(short)f2bf(a[1]); t[2]=(short)f2bf(a[2]); t[3]=(short)f2bf(a[3]);
  t[4]=(short)f2bf(b[0]); t[5]=(short)f2bf(b[1]); t[6]=(short)f2bf(b[2]); t[7]=(short)f2bf(b[3]);
  return t;
}

// async global->LDS, 16B per lane, linear LDS dest (wave-uniform base + lane*16)
__device__ __forceinline__ void gload16(const void* g, void* l){
  __builtin_amdgcn_global_load_lds((const __attribute__((address_space(1))) void*)g,
                                   (__attribute__((address_space(3))) void*)l, 16, 0, 0);
}

// stage a [ROWS][64] bf16 chunk as the XOR-swizzled image via global_load_lds.
// LDS slot (row, blk16) holds global 16B block (blk16 ^ (row&7)) of that row.
template<int CALLS>
__device__ __forceinline__ void gstage(const char* src, size_t rowStrideB, int chunkByteOff,
                                       char* lds, int wid, int lane){
#pragma unroll
  for (int i=0;i<CALLS;++i){
    int base = (wid*CALLS + i)*1024;
    int off  = base + lane*16;
    int row  = off >> 7;
    int blk  = ((off >> 4) & 7) ^ (row & 7);
    gload16(src + (size_t)row*rowStrideB + chunkByteOff + blk*16, lds + base);
  }
}

// reg-staged LDS write of 4x16B for one row-half, same swizzled image
__device__ __forceinline__ void lds_store4(char* buf, int row, int rowBytes, int khByte,
                                           int swzMask, const shortx8* v){
#pragma unroll
  for (int q=0;q<4;++q){
    int off = row*rowBytes + khByte + q*16;
    off ^= (row & swzMask) << 4;
    *(shortx8*)(buf + off) = v[q];
  }
}

__device__ __forceinline__ void stage_bf16(char* buf, const u16* gsrc, size_t srcRowBytes, int tid){
  int row = tid >> 1, kh = tid & 1;
  const char* p = (const char*)gsrc + (size_t)row*srcRowBytes + kh*64;
  shortx8 v[4];
#pragma unroll
  for (int q=0;q<4;++q) v[q] = *(const shortx8*)(p + q*16);
  lds_store4(buf, row, 128, kh*64, 7, v);
}

__device__ __forceinline__ shortx8 lds_frag(const char* buf, int row, int rowBytes, int kByte,
                                            int swzMask, int lane){
  int off = row*rowBytes + kByte + ((lane>>4)<<4);
  off ^= (row & swzMask) << 4;
  return *(const shortx8*)(buf + off);
}

template<int MF, int NF>
__device__ __forceinline__ void mma64(const char* As, const char* Bs, int wm, int wn, int lane,
                                      floatx4 acc[MF][NF]){
#pragma unroll
  for (int kk=0; kk<2; ++kk){
    shortx8 a[MF], b[NF];
#pragma unroll
    for (int i=0;i<MF;++i) a[i] = lds_frag(As, wm + i*16 + (lane&15), 128, kk*64, 7, lane);
#pragma unroll
    for (int j=0;j<NF;++j) b[j] = lds_frag(Bs, wn + j*16 + (lane&15), 128, kk*64, 7, lane);
#pragma unroll
    for (int i=0;i<MF;++i)
#pragma unroll
      for (int j=0;j<NF;++j)
        acc[i][j] = __builtin_amdgcn_mfma_f32_16x16x32_bf16(a[i], b[j], acc[i][j], 0, 0, 0);
  }
}

// split phase: ds_read all frags first, then MFMAs on regs (pipeline-friendly)
template<int MF, int NF>
__device__ __forceinline__ void frags_load(const char* As, const char* Bs, int wm, int wn, int lane,
                                           shortx8 a[2][MF], shortx8 b[2][NF]){
#pragma unroll
  for (int kk=0;kk<2;++kk){
#pragma unroll
    for (int i=0;i<MF;++i) a[kk][i] = lds_frag(As, wm + i*16 + (lane&15), 128, kk*64, 7, lane);
#pragma unroll
    for (int j=0;j<NF;++j) b[kk][j] = lds_frag(Bs, wn + j*16 + (lane&15), 128, kk*64, 7, lane);
  }
}
template<int MF, int NF>
__device__ __forceinline__ void frags_mma(shortx8 a[2][MF], shortx8 b[2][NF], floatx4 acc[MF][NF]){
#pragma unroll
  for (int kk=0;kk<2;++kk)
#pragma unroll
    for (int i=0;i<MF;++i)
#pragma unroll
      for (int j=0;j<NF;++j)
        acc[i][j] = __builtin_amdgcn_mfma_f32_16x16x32_bf16(a[kk][i], b[kk][j], acc[i][j], 0, 0, 0);
}

// bijective XCD chunking (nwg % 8 == 0)
__device__ __forceinline__ int xcd_swz(int bid, int nwg){
  int q = nwg >> 3;
  return (bid & 7)*q + (bid >> 3);
}

// ---------- prep: fp32 (S,Ksrc,N) slice [kSrcOff, kSrcOff+Kuse) -> bf16 (S,N,Kpad) at kDstOff ----------
__global__ __launch_bounds__(256) void transpose_w2(const float* __restrict__ src,
                                                    u16* __restrict__ dst,
                                                    int sKstride, int kSrcOff, int Kuse,
                                                    int N, int Kpad, int kDstOff){
  __shared__ float tile[32][33];
  int s = blockIdx.z;
  int k0 = blockIdx.x*32, n0 = blockIdx.y*32;
  int tx = threadIdx.x & 31, ty = threadIdx.x >> 5;
#pragma unroll
  for (int r=0;r<4;++r){
    int k = k0 + ty*4 + r;
    float v = (k < Kuse) ? src[((size_t)s*sKstride + kSrcOff + k)*N + n0 + tx] : 0.f;
    tile[ty*4+r][tx] = v;
  }
  __syncthreads();
#pragma unroll
  for (int r=0;r<4;++r){
    int n = n0 + ty*4 + r;
    dst[((size_t)s*N + n)*Kpad + kDstOff + k0 + tx] = f2bf(tile[tx][ty*4+r]);
  }
}

// ---------- bn: h2 = (relu(gs @ w1 + b1)) @ w2 + b2 -> h2b ; side-writes gsb (bf16 gs) ----------
__global__ __launch_bounds__(256) void k_bn(const float* __restrict__ gs,
     const u16* __restrict__ w1t, const u16* __restrict__ w2t,
     const float* __restrict__ b1, const float* __restrict__ b2,
     u16* __restrict__ h2b, u16* __restrict__ gsb){
  __shared__ __align__(16) char SMB[40960];
  int tid = threadIdx.x, lane = tid & 63, wid = tid >> 6;
  int nb = xcd_swz(blockIdx.x, 1152);
  int m0 = (nb & 63)*128, s = nb >> 6;
  floatx4 acc[2][2] = {};
  const char*  Bsrc = (const char*)w1t + (size_t)s*32*1024;
  size_t rowIdx = ((size_t)(m0 + (tid>>1))*SS + s)*DD + (tid&1)*32;
  const float* Ags  = gs + rowIdx;
  u16*         Gsb  = gsb + rowIdx;
  floatx4 fr[8];
  gstage<1>(Bsrc, 1024, 0, SMB+32768, wid, lane);
#pragma unroll
  for (int q=0;q<8;++q) fr[q] = *(const floatx4*)(Ags + q*4);
  for (int c=0;c<8;++c){
    char* Asc = SMB + (c&1)*16384;
    char* Bsc = SMB + 32768 + (c&1)*4096;
    { shortx8 v[4];
#pragma unroll
      for (int q=0;q<4;++q) v[q] = pack8v(fr[2*q], fr[2*q+1]);
      u16* gp = Gsb + c*64;
#pragma unroll
      for (int q=0;q<4;++q) *(shortx8*)(gp + q*8) = v[q];   // bf16 image of gs
      lds_store4(Asc, tid>>1, 128, (tid&1)*64, 7, v); }
    __syncthreads();
    int cn = c+1;
    if (cn < 8){
      gstage<1>(Bsrc, 1024, cn*128, SMB + 32768 + (cn&1)*4096, wid, lane);
      const float* p = Ags + cn*64;
#pragma unroll
      for (int q=0;q<8;++q) fr[q] = *(const floatx4*)(p + q*4);
    }
    mma64<2,2>(Asc, Bsc, wid*32, 0, lane, acc);
  }
  __syncthreads();
  char* G1  = SMB;
  char* W2s = SMB + 8192;
#pragma unroll
  for (int i=0;i<2;++i)
#pragma unroll
   for (int j=0;j<2;++j){
    int col = j*16 + (lane&15);
    float bias = b1[s*32 + col];
#pragma unroll
    for (int r=0;r<4;++r){
      int row = wid*32 + i*16 + ((lane>>4)<<2) + r;
      float v = fmaxf(acc[i][j][r] + bias, 0.f);
      int off = (row*64 + col*2) ^ ((row&3)<<4);
      *(u16*)(G1 + off) = f2bf(v);
    }
  }
  if (tid < 32){
    const u16* p = w2t + (size_t)s*32*32 + tid*32;
#pragma unroll
    for (int q=0;q<4;++q){
      int off = (tid*64 + q*16) ^ ((tid&3)<<4);
      *(shortx8*)(W2s + off) = *(const shortx8*)(p + q*8);
    }
  }
  __syncthreads();
  floatx4 acc2[2][2] = {};
  {
    shortx8 a[2], b[2];
#pragma unroll
    for (int i=0;i<2;++i) a[i] = lds_frag(G1,  wid*32 + i*16 + (lane&15), 64, 0, 3, lane);
#pragma unroll
    for (int j=0;j<2;++j) b[j] = lds_frag(W2s, j*16 + (lane&15),          64, 0, 3, lane);
#pragma unroll
    for (int i=0;i<2;++i)
#pragma unroll
      for (int j=0;j<2;++j)
        acc2[i][j] = __builtin_amdgcn_mfma_f32_16x16x32_bf16(a[i], b[j], acc2[i][j], 0,0,0);
  }
#pragma unroll
  for (int i=0;i<2;++i)
#pragma unroll
   for (int j=0;j<2;++j){
    int col = j*16 + (lane&15);
    float bias = b2[s*32 + col];
#pragma unroll
    for (int r=0;r<4;++r){
      int row = wid*32 + i*16 + ((lane>>4)<<2) + r;
      h2b[((size_t)(m0+row)*SS + s)*32 + col] = f2bf(acc2[i][j][r] + bias);
    }
  }
}

// ---------- gm + age: gfa (B,192) bf16 (cols 144..191 zero) ----------
__global__ __launch_bounds__(256) void k_gm(const u16* __restrict__ h2b,
     const u16* __restrict__ w1t, const u16* __restrict__ w2t,
     const float* __restrict__ b1, const float* __restrict__ b2,
     const float* __restrict__ ta, const float* __restrict__ aw1, const float* __restrict__ ab1,
     const float* __restrict__ aw2, const float* __restrict__ ab2,
     u16* __restrict__ gfab){
  __shared__ __align__(16) char As[128*128];
  __shared__ __align__(16) char Bs[128*128];
  __shared__ __align__(16) char G1[128*256];
  int tid=threadIdx.x, lane=tid&63, w=tid>>6;
  int m0 = blockIdx.x*128;
  floatx4 acc[2][8] = {};
  for (int c=0;c<9;++c){
    __syncthreads();
    stage_bf16(As, h2b + (size_t)m0*576 + c*64, 1152, tid);
    stage_bf16(Bs, w1t + c*64,                 1152, tid);
    __syncthreads();
    mma64<2,8>(As, Bs, w*32, 0, lane, acc);
  }
#pragma unroll
  for (int i=0;i<2;++i)
#pragma unroll
   for (int j=0;j<8;++j){
    int col = j*16 + (lane&15);
    float bias = b1[col];
#pragma unroll
    for (int r=0;r<4;++r){
      int row = w*32 + i*16 + ((lane>>4)<<2) + r;
      float v = fmaxf(acc[i][j][r] + bias, 0.f);
      int off = (row*256 + col*2) ^ ((row&7)<<4);
      *(u16*)(G1 + off) = f2bf(v);
    }
  }
  floatx4 acc2[2][8] = {};
  for (int c2=0;c2<2;++c2){
    __syncthreads();
    stage_bf16(Bs, w2t + c2*64, 256, tid);
    __syncthreads();
#pragma unroll
    for (int kk=0;kk<2;++kk){
      shortx8 a[2], b[8];
#pragma unroll
      for (int i=0;i<2;++i){
        int row = w*32 + i*16 + (lane&15);
        int off = (row*256 + c2*128 + kk*64 + ((lane>>4)<<4)) ^ ((row&7)<<4);
        a[i] = *(const shortx8*)(G1 + off);
      }
#pragma unroll
      for (int j=0;j<8;++j) b[j] = lds_frag(Bs, j*16 + (lane&15), 128, kk*64, 7, lane);
#pragma unroll
      for (int i=0;i<2;++i)
#pragma unroll
        for (int j=0;j<8;++j)
          acc2[i][j] = __builtin_amdgcn_mfma_f32_16x16x32_bf16(a[i], b[j], acc2[i][j], 0,0,0);
    }
  }
#pragma unroll
  for (int i=0;i<2;++i)
#pragma unroll
   for (int j=0;j<8;++j){
    int col = j*16 + (lane&15);
    float bias = b2[col];
#pragma unroll
    for (int r=0;r<4;++r){
      int row = w*32 + i*16 + ((lane>>4)<<2) + r;
      gfab[(size_t)(m0+row)*192 + col] = f2bf(acc2[i][j][r] + bias);
    }
  }
  if (tid < 128){
    int bidx = m0 + tid;
    float t = ta[bidx];
    float a1[16];
#pragma unroll
    for (int j2=0;j2<16;++j2){ float v = t*aw1[j2] + ab1[j2]; a1[j2] = fmaxf(v, 0.f); }
#pragma unroll
    for (int m=0;m<16;++m){
      float v = ab2[m];
#pragma unroll
      for (int j2=0;j2<16;++j2) v += a1[j2]*aw2[j2*16+m];
      gfab[(size_t)bidx*192 + 128 + m] = f2bf(v);
    }
    shortx8 zz = {};
#pragma unroll
    for (int z=0;z<6;++z) *(shortx8*)(gfab + (size_t)bidx*192 + 144 + z*8) = zz;
  }
}

// ---------- fc1: counted-vmcnt 3A/2B pipeline, pure bf16 sources ----------
__global__ __launch_bounds__(256) void k_fc1(const u16* __restrict__ gfab,
     const u16* __restrict__ gsb, const u16* __restrict__ w1t,
     const float* __restrict__ b1, u16* __restrict__ y1b){
  __shared__ __align__(16) char SMB[81920];   // A: 3x16K @0, B: 2x16K @49152
  int tid=threadIdx.x, lane=tid&63, wid=tid>>6;
  int nb = xcd_swz(blockIdx.x, 4608);
  int n0=(nb&3)*128, m0=((nb>>2)&63)*128, s=nb>>8;
  int wm=(wid>>1)*64, wn=(wid&1)*64;
  floatx4 acc[4][4] = {};
  const char* Ag   = (const char*)gfab + (size_t)m0*384;
  const char* Agl  = (const char*)gsb + ((size_t)m0*SS + s)*1024;
  const char* Bsrc = (const char*)w1t + ((size_t)s*512+n0)*1408;
#define F1_ISSA(t) do{ int _t=(t); char* _d = SMB + (_t%3)*16384; \
    if (_t<3) gstage<4>(Ag, 384, _t*128, _d, wid, lane); \
    else      gstage<4>(Agl, (size_t)SS*1024, _t*128-384, _d, wid, lane); }while(0)
#define F1_ISSB(t) gstage<4>(Bsrc, 1408, (t)*128, SMB+49152+((t)&1)*16384, wid, lane)
  F1_ISSB(0); F1_ISSA(0); F1_ISSA(1);
#pragma unroll 1
  for (int c=0;c<11;++c){
    if (c<10) asm volatile("s_waitcnt vmcnt(4)" ::: "memory");
    else      asm volatile("s_waitcnt vmcnt(0)" ::: "memory");
    __builtin_amdgcn_s_barrier();
    __builtin_amdgcn_sched_barrier(0);
    shortx8 a[2][4], b[2][4];
    frags_load<4,4>(SMB+(c%3)*16384, SMB+49152+(c&1)*16384, wm, wn, lane, a, b);
    if (c+1<11) F1_ISSB(c+1);
    if (c+2<11) F1_ISSA(c+2);
    frags_mma<4,4>(a, b, acc);
  }
  __syncthreads();
  char* OT = SMB;
#pragma unroll
  for (int i=0;i<4;++i)
#pragma unroll
   for (int j=0;j<4;++j){
    int col = wn + j*16 + (lane&15);
    float bias = b1[(size_t)s*512 + n0 + col];
#pragma unroll
    for (int r=0;r<4;++r){
      int row = wm + i*16 + ((lane>>4)<<2) + r;
      float v = fmaxf(acc[i][j][r] + bias, 0.f);
      int off = (row*256 + col*2) ^ ((row&7)<<4);
      *(u16*)(OT + off) = f2bf(v);
    }
  }
  __syncthreads();
  {
    int row = tid>>1, half = tid&1;
    u16* gp = y1b + ((size_t)(m0+row)*SS + s)*DD + n0 + half*64;
#pragma unroll
    for (int q=0;q<8;++q){
      int off = (row*256 + half*128 + q*16) ^ ((row&7)<<4);
      *(shortx8*)(gp + q*8) = *(const shortx8*)(OT + off);
    }
  }
}

// ---------- fc2: counted-vmcnt 3A/2B pipeline; out = y1 @ w2 + b2 + gs ----------
__global__ __launch_bounds__(256) void k_fc2(const u16* __restrict__ y1b,
     const u16* __restrict__ gsb, const u16* __restrict__ w2t,
     const float* __restrict__ b2, float* __restrict__ out){
  __shared__ __align__(16) char SMB[81920];
  int tid=threadIdx.x, lane=tid&63, wid=tid>>6;
  int nb = xcd_swz(blockIdx.x, 4608);
  int n0=(nb&3)*128, m0=((nb>>2)&63)*128, s=nb>>8;
  int wm=(wid>>1)*64, wn=(wid&1)*64;
  floatx4 acc[4][4] = {};
  const char* Asrc = (const char*)y1b + ((size_t)m0*SS + s)*1024;
  const char* Bsrc = (const char*)w2t + ((size_t)s*512 + n0)*1024;
#define F2_ISSA(t) gstage<4>(Asrc, (size_t)SS*1024, (t)*128, SMB+((t)%3)*16384, wid, lane)
#define F2_ISSB(t) gstage<4>(Bsrc, 1024, (t)*128, SMB+49152+((t)&1)*16384, wid, lane)
  F2_ISSB(0); F2_ISSA(0); F2_ISSA(1);
#pragma unroll 1
  for (int c=0;c<8;++c){
    if (c<7) asm volatile("s_waitcnt vmcnt(4)" ::: "memory");
    else     asm volatile("s_waitcnt vmcnt(0)" ::: "memory");
    __builtin_amdgcn_s_barrier();
    __builtin_amdgcn_sched_barrier(0);
    shortx8 a[2][4], b[2][4];
    frags_load<4,4>(SMB+(c%3)*16384, SMB+49152+(c&1)*16384, wm, wn, lane, a, b);
    if (c+1<8) F2_ISSB(c+1);
    if (c+2<8) F2_ISSA(c+2);
    frags_mma<4,4>(a, b, acc);
  }
  __syncthreads();
  float* SMF = (float*)SMB;   // 64KB fp32 outbuf
#pragma unroll
  for (int i=0;i<4;++i)
#pragma unroll
   for (int j=0;j<4;++j){
    int col = wn + j*16 + (lane&15);
#pragma unroll
    for (int r=0;r<4;++r){
      int row = wm + i*16 + ((lane>>4)<<2) + r;
      int off = (row*512 + col*4) ^ ((row&7)<<4);
      *(float*)((char*)SMF + off) = acc[i][j][r];
    }
  }
  __syncthreads();
  {
    int row = tid>>1, half = tid&1;
    size_t gidx = ((size_t)(m0+row)*SS + s)*DD + n0 + half*64;
    const float* bp = b2 + (size_t)s*512 + n0 + half*64;
    const u16*   gp = gsb + gidx;
#pragma unroll
    for (int q2=0;q2<8;++q2){
      shortx8 gv = *(const shortx8*)(gp + q2*8);
      int off0 = (row*512 + half*256 + (2*q2)*16)   ^ ((row&7)<<4);
      int off1 = (row*512 + half*256 + (2*q2+1)*16) ^ ((row&7)<<4);
      floatx4 v0 = *(const floatx4*)((char*)SMF + off0);
      floatx4 v1 = *(const floatx4*)((char*)SMF + off1);
      floatx4 b0 = *(const floatx4*)(bp + q2*8);
      floatx4 b1v= *(const floatx4*)(bp + q2*8 + 4);
      floatx4 g0, g1;
      g0[0]=bf2f((u16)gv[0]); g0[1]=bf2f((u16)gv[1]); g0[2]=bf2f((u16)gv[2]); g0[3]=bf2f((u16)gv[3]);
      g1[0]=bf2f((u16)gv[4]); g1[1]=bf2f((u16)gv[5]); g1[2]=bf2f((u16)gv[6]); g1[3]=bf2f((u16)gv[7]);
      *(floatx4*)(out + gidx + q2*8)     = v0 + b0 + g0;
      *(floatx4*)(out + gidx + q2*8 + 4) = v1 + b1v + g1;
    }
  }
}

// ---------- launch ----------
extern "C" void kernel_launch(void* const* d_in, const int* in_sizes, int n_in,
                              void* d_out, int out_size, void* d_ws, size_t ws_size,
                              hipStream_t stream){
  (void)in_sizes; (void)n_in; (void)out_size; (void)ws_size;
  const float* gs   = (const float*)d_in[1];
  const float* ta   = (const float*)d_in[2];
  const float* bnw1 = (const float*)d_in[3];
  const float* bnb1 = (const float*)d_in[4];
  const float* bnw2 = (const float*)d_in[5];
  const float* bnb2 = (const float*)d_in[6];
  const float* gmw1 = (const float*)d_in[7];
  const float* gmb1 = (const float*)d_in[8];
  const float* gmw2 = (const float*)d_in[9];
  const float* gmb2 = (const float*)d_in[10];
  const float* aw1  = (const float*)d_in[11];
  const float* ab1  = (const float*)d_in[12];
  const float* aw2  = (const float*)d_in[13];
  const float* ab2  = (const float*)d_in[14];
  const float* fcw1 = (const float*)d_in[15];
  const float* fcb1 = (const float*)d_in[16];
  const float* fcw2 = (const float*)d_in[17];
  const float* fcb2 = (const float*)d_in[18];

  char* ws = (char*)d_ws;                       // ~322 MB total
  u16* fcW1t = (u16*)(ws + 0);                  // 12,976,128
  u16* fcW2t = (u16*)(ws + 12976128);           //  9,437,184
  u16* bnW1t = (u16*)(ws + 22413312);           //    589,824
  u16* bnW2t = (u16*)(ws + 23003136);           //     36,864
  u16* gmW1t = (u16*)(ws + 23040000);           //    147,456
  u16* gmW2t = (u16*)(ws + 23187456);           //     32,768
  u16* h2b   = (u16*)(ws + 23220224);           //  9,437,184
  u16* gfab  = (u16*)(ws + 32657408);           //  3,145,728 (B x 192)
  u16* y1b   = (u16*)(ws + 35803136);           // 150,994,944
  u16* gsb   = (u16*)(ws + 186798080);          // 150,994,944 (end 337,793,024)
  float* out = (float*)d_out;

  dim3 blk(256);
  transpose_w2<<<dim3(16,1,18),  blk, 0, stream>>>(bnw1, bnW1t, 512, 0, 512,  32, 512, 0);
  transpose_w2<<<dim3(1,1,18),   blk, 0, stream>>>(bnw2, bnW2t,  32, 0,  32,  32,  32, 0);
  transpose_w2<<<dim3(18,4,1),   blk, 0, stream>>>(gmw1, gmW1t, 576, 0, 576, 128, 576, 0);
  transpose_w2<<<dim3(4,4,1),    blk, 0, stream>>>(gmw2, gmW2t, 128, 0, 128, 128, 128, 0);
  transpose_w2<<<dim3(6,16,18),  blk, 0, stream>>>(fcw1, fcW1t, 656, 0,   144, 512, 704, 0);
  transpose_w2<<<dim3(16,16,18), blk, 0, stream>>>(fcw1, fcW1t, 656, 144, 512, 512, 704, 192);
  transpose_w2<<<dim3(16,16,18), blk, 0, stream>>>(fcw2, fcW2t, 512, 0, 512, 512, 512, 0);

  k_bn <<<dim3(1152), blk, 0, stream>>>(gs, bnW1t, bnW2t, bnb1, bnb2, h2b, gsb);
  k_gm <<<dim3(64),   blk, 0, stream>>>(h2b, gmW1t, gmW2t, gmb1, gmb2, ta, aw1, ab1, aw2, ab2, gfab);
  k_fc1<<<dim3(4608), blk, 0, stream>>>(gfab, gsb, fcW1t, fcb1, y1b);
  k_fc2<<<dim3(4608), blk, 0, stream>>>(y1b, gsb, fcW2t, fcb2, out);
}